// Round 5
// baseline (474.086 us; speedup 1.0000x reference)
//
#include <hip/hip_runtime.h>
#include <stdint.h>

#define N_TOK 2048
#define DM 1024
#define DI 2816
#define NE 8
#define NSLOT (N_TOK * 2)   // 4096 (token, expert) slots
#define BKP 72              // LDS k-stride (shorts): 64 + 8 pad
#define MAXRT 40            // max row tiles: sum_e ceil(cnt_e/128) <= 39
#define NBLK (N_TOK / 4)    // 512 router/gather blocks (4 tokens each)

typedef __bf16 bf16x8 __attribute__((ext_vector_type(8)));
typedef float f32x4 __attribute__((ext_vector_type(4)));

__device__ __forceinline__ unsigned short f2bf(float f) {
    unsigned u = __builtin_bit_cast(unsigned, f);
    u += 0x7fffu + ((u >> 16) & 1u);   // RNE
    return (unsigned short)(u >> 16);
}
__device__ __forceinline__ unsigned pack2bf(float a, float b) {
    return (unsigned)f2bf(a) | ((unsigned)f2bf(b) << 16);
}

__device__ __forceinline__ f32x4 mfma_bf16(bf16x8 a, bf16x8 b, f32x4 c) {
    return __builtin_amdgcn_mfma_f32_16x16x32_bf16(a, b, c, 0, 0, 0);
}

// ---------------- router: logits, softmax, top2, per-block hist -------------
__global__ __launch_bounds__(256) void k_router(
    const float* __restrict__ x, const float* __restrict__ wr,
    float* __restrict__ probsum, int* __restrict__ te, float* __restrict__ tw,
    unsigned* __restrict__ hist)
{
    __shared__ int te_s[8];
    __shared__ float ps[4][NE];
    int w = threadIdx.x >> 6, lane = threadIdx.x & 63;
    int n = blockIdx.x * 4 + w;
    const float* xr = x + (size_t)n * DM;

    float acc[NE];
#pragma unroll
    for (int e = 0; e < NE; e++) acc[e] = 0.f;
#pragma unroll
    for (int it = 0; it < DM / 64; it++) {
        float xv = xr[lane + it * 64];
#pragma unroll
        for (int e = 0; e < NE; e++) acc[e] += xv * wr[e * DM + lane + it * 64];
    }
#pragma unroll
    for (int e = 0; e < NE; e++) {
        float v = acc[e];
#pragma unroll
        for (int off = 32; off; off >>= 1) v += __shfl_xor(v, off);
        acc[e] = v;
    }
    float m = acc[0];
#pragma unroll
    for (int e = 1; e < NE; e++) m = fmaxf(m, acc[e]);
    float p[NE], s = 0.f;
#pragma unroll
    for (int e = 0; e < NE; e++) { p[e] = __expf(acc[e] - m); s += p[e]; }
    float inv = 1.f / s;
#pragma unroll
    for (int e = 0; e < NE; e++) p[e] *= inv;
    int i0 = 0;
#pragma unroll
    for (int e = 1; e < NE; e++) if (p[e] > p[i0]) i0 = e;
    int i1 = (i0 == 0) ? 1 : 0;
#pragma unroll
    for (int e = 0; e < NE; e++) if (e != i0 && p[e] > p[i1]) i1 = e;
    float w0 = p[i0] / (p[i0] + p[i1]);
    float w1 = 1.f - w0;

    if (lane == 0) {
        te[2 * n] = i0; te[2 * n + 1] = i1;
        tw[2 * n] = w0; tw[2 * n + 1] = w1;
        te_s[2 * w] = i0; te_s[2 * w + 1] = i1;
    }
    if (lane < NE) ps[w][lane] = p[lane];   // p identical across lanes
    __syncthreads();

    if (threadIdx.x < NE) {
        float s4 = ps[0][threadIdx.x] + ps[1][threadIdx.x] +
                   ps[2][threadIdx.x] + ps[3][threadIdx.x];
        atomicAdd(&probsum[threadIdx.x], s4);   // 8 per block, non-returning
    }
    if (w == 0) {
        unsigned v = 0;
        if (lane < NE) {
            int c = 0;
#pragma unroll
            for (int i = 0; i < 8; i++) c += (te_s[i] == lane);
            v = (unsigned)c << (4 * lane);
        }
        v |= __shfl_xor(v, 1); v |= __shfl_xor(v, 2); v |= __shfl_xor(v, 4);
        if (lane == 0) hist[blockIdx.x] = v;
    }
}

// ---------------- finalize: counts/base/rtmap/aux + per-block slot offsets --
__global__ __launch_bounds__(512) void k_finalize(
    const unsigned* __restrict__ hist, const float* __restrict__ probsum,
    int* __restrict__ counts, int* __restrict__ base,
    int* __restrict__ nrt_out, unsigned short* __restrict__ rtmap,
    unsigned short* __restrict__ blockoff, float* __restrict__ aux_out)
{
    __shared__ int cnts_s[NE], base_s[NE];
    int tid = threadIdx.x;
    int e = tid >> 6, lane = tid & 63;

    int c[8], t = 0;
#pragma unroll
    for (int j = 0; j < 8; j++) {
        c[j] = (int)((hist[lane * 8 + j] >> (4 * e)) & 15u);
        t += c[j];
    }
    int incl = t;
#pragma unroll
    for (int off = 1; off < 64; off <<= 1) {
        int v = __shfl_up(incl, off);
        if (lane >= off) incl += v;
    }
    int excl = incl - t;
    if (lane == 63) cnts_s[e] = incl;
    __syncthreads();

    if (tid == 0) {
        int b = 0, nrt = 0; float aux = 0.f;
        for (int ee = 0; ee < NE; ee++) {
            int cc = cnts_s[ee];
            base_s[ee] = b;
            base[ee] = b;
            counts[ee] = cc;
            b += cc;
            aux += ((float)cc / (float)(N_TOK * 2)) *
                   (probsum[ee] / (float)N_TOK);
            int nt = (cc + 127) >> 7;
            for (int mt = 0; mt < nt; mt++)
                rtmap[nrt++] = (unsigned short)((ee << 8) | mt);
        }
        nrt_out[0] = nrt;
        aux_out[0] = aux * (float)NE;
    }
    __syncthreads();

    int run = base_s[e] + excl;
#pragma unroll
    for (int j = 0; j < 8; j++) {
        blockoff[(lane * 8 + j) * NE + e] = (unsigned short)run;
        run += c[j];
    }
}

// ---------------- gather: deterministic slots + fp32->bf16 copy -------------
__global__ __launch_bounds__(256) void k_gather(
    const float* __restrict__ x, const int* __restrict__ te,
    const unsigned short* __restrict__ blockoff,
    int* __restrict__ slots, unsigned short* __restrict__ Xg)
{
    __shared__ int te_s[8];
    int w = threadIdx.x >> 6, lane = threadIdx.x & 63;
    int n = blockIdx.x * 4 + w;
    if (lane == 0) {
        te_s[2 * w] = te[2 * n];
        te_s[2 * w + 1] = te[2 * n + 1];
    }
    __syncthreads();
    int s0 = 0, s1 = 0;
    if (lane == 0) {
        int i0 = 2 * w, i1 = 2 * w + 1;
        int e0 = te_s[i0], e1 = te_s[i1];
        int r0 = 0, r1 = 0;
        for (int j = 0; j < i0; j++) r0 += (te_s[j] == e0);
        for (int j = 0; j < i1; j++) r1 += (te_s[j] == e1);
        s0 = blockoff[blockIdx.x * NE + e0] + r0;
        s1 = blockoff[blockIdx.x * NE + e1] + r1;
        slots[2 * n] = s0; slots[2 * n + 1] = s1;
    }
    s0 = __shfl(s0, 0); s1 = __shfl(s1, 0);

    const float4* xr = (const float4*)(x + (size_t)n * DM);
    float4 f0 = xr[lane * 4 + 0], f1 = xr[lane * 4 + 1];
    float4 f2 = xr[lane * 4 + 2], f3 = xr[lane * 4 + 3];
    uint4 lo = make_uint4(pack2bf(f0.x, f0.y), pack2bf(f0.z, f0.w),
                          pack2bf(f1.x, f1.y), pack2bf(f1.z, f1.w));
    uint4 hi = make_uint4(pack2bf(f2.x, f2.y), pack2bf(f2.z, f2.w),
                          pack2bf(f3.x, f3.y), pack2bf(f3.z, f3.w));
    uint4* d0 = (uint4*)(Xg + (size_t)s0 * DM) + lane * 2;
    uint4* d1 = (uint4*)(Xg + (size_t)s1 * DM) + lane * 2;
    d0[0] = lo; d0[1] = hi;
    d1[0] = lo; d1[1] = hi;
}

// ---------------- pack: fp32 [R][C] -> bf16 [C][R] (per expert) -------------
__device__ __forceinline__ void pack_body(
    const float* __restrict__ s, unsigned short* __restrict__ d, int R, int C)
{
    __shared__ unsigned short T[64][66];
    int r0 = blockIdx.y * 64, c0 = blockIdx.x * 64;
    int t = threadIdx.x;
    int ri = t >> 2, cc = (t & 3) * 16;
    const float4* sp = (const float4*)(s + (size_t)(r0 + ri) * C + c0 + cc);
    float4 f0 = sp[0], f1 = sp[1], f2 = sp[2], f3 = sp[3];
    unsigned short* tp = &T[ri][cc];
    *(unsigned*)(tp + 0)  = pack2bf(f0.x, f0.y);
    *(unsigned*)(tp + 2)  = pack2bf(f0.z, f0.w);
    *(unsigned*)(tp + 4)  = pack2bf(f1.x, f1.y);
    *(unsigned*)(tp + 6)  = pack2bf(f1.z, f1.w);
    *(unsigned*)(tp + 8)  = pack2bf(f2.x, f2.y);
    *(unsigned*)(tp + 10) = pack2bf(f2.z, f2.w);
    *(unsigned*)(tp + 12) = pack2bf(f3.x, f3.y);
    *(unsigned*)(tp + 14) = pack2bf(f3.z, f3.w);
    __syncthreads();
    int co = t >> 2, rr = (t & 3) * 16;
    unsigned w0 = (unsigned)T[rr + 0][co] | ((unsigned)T[rr + 1][co] << 16);
    unsigned w1 = (unsigned)T[rr + 2][co] | ((unsigned)T[rr + 3][co] << 16);
    unsigned w2 = (unsigned)T[rr + 4][co] | ((unsigned)T[rr + 5][co] << 16);
    unsigned w3 = (unsigned)T[rr + 6][co] | ((unsigned)T[rr + 7][co] << 16);
    unsigned w4 = (unsigned)T[rr + 8][co] | ((unsigned)T[rr + 9][co] << 16);
    unsigned w5 = (unsigned)T[rr + 10][co] | ((unsigned)T[rr + 11][co] << 16);
    unsigned w6 = (unsigned)T[rr + 12][co] | ((unsigned)T[rr + 13][co] << 16);
    unsigned w7 = (unsigned)T[rr + 14][co] | ((unsigned)T[rr + 15][co] << 16);
    unsigned short* dp = d + (size_t)(c0 + co) * R + r0 + rr;
    *(uint4*)(dp + 0) = make_uint4(w0, w1, w2, w3);
    *(uint4*)(dp + 8) = make_uint4(w4, w5, w6, w7);
}

__global__ __launch_bounds__(256) void k_pack(
    const float* __restrict__ src, unsigned short* __restrict__ dst,
    int R, int C)
{
    pack_body(src + (size_t)blockIdx.z * R * C,
              dst + (size_t)blockIdx.z * R * C, R, C);
}

// fused Wg+Wu pack: z in [0,16), z<8 -> Wg expert z, else Wu expert z-8
__global__ __launch_bounds__(256) void k_pack2(
    const float* __restrict__ srcA, unsigned short* __restrict__ dstA,
    const float* __restrict__ srcB, unsigned short* __restrict__ dstB,
    int R, int C)
{
    int z = blockIdx.z;
    const float* s = (z < NE ? srcA : srcB) + (size_t)(z & 7) * R * C;
    unsigned short* d = (z < NE ? dstA : dstB) + (size_t)(z & 7) * R * C;
    pack_body(s, d, R, C);
}

// ---------------- phase 1: [Xg rows] @ (Wg|Wu) -> silu*u -> H (bf16) --------
// nc-major compacted tile order (consecutive blocks share the B panel) +
// XCD-chunked blockIdx swizzle (panel group stays on one XCD's L2).
template<bool PK>
__global__ __launch_bounds__(256, 4) void k_ffn1(
    const unsigned short* __restrict__ Xg,
    const float* __restrict__ wg, const float* __restrict__ wu,
    const unsigned short* __restrict__ wgp, const unsigned short* __restrict__ wup,
    const int* __restrict__ counts, const int* __restrict__ base,
    const int* __restrict__ nrt_p, const unsigned short* __restrict__ rtmap,
    unsigned short* __restrict__ H)
{
    __shared__ unsigned short As[128 * BKP];
    __shared__ unsigned short Bg[64 * BKP];
    __shared__ unsigned short Bu[64 * BKP];

    int tid = threadIdx.x;
    int w = tid >> 6, lane = tid & 63, quad = lane >> 4, ln = lane & 15;
    int ar = tid >> 1;
    int ak = (tid & 1) * 32;
    // fp32-staging map
    int kp = tid >> 3, n0 = (tid & 7) * 8;
    int kpsw2 = ((((kp >> 2) ^ (tid & 7)) << 2) | (kp & 3)) * 2;
    // packed-staging map: thread -> (n row, chunk pair)
    int nb = tid >> 2;
    int cA = (tid & 3) * 2;                       // chunks cA, cA+1 (8 shorts each)
    int boff0 = nb * BKP + ((cA ^ ((nb >> 3) & 7)) * 8);
    int boff1 = nb * BKP + (((cA + 1) ^ ((nb >> 3) & 7)) * 8);
    int bsrc = cA * 8;                            // k-offset (shorts) within row

    const int NCT = DI / 64;   // 44
    int nrt_v = nrt_p[0];
    int total = nrt_v * NCT;
    // XCD-chunked swizzle: gridDim.x divisible by 8
    int wgid = (blockIdx.x & 7) * (gridDim.x >> 3) + (blockIdx.x >> 3);

    for (int tix = wgid; tix < total; tix += gridDim.x) {
        int nc = tix / nrt_v;              // nc-major: rt is the minor index
        int rt = tix - nc * nrt_v;
        int nc0 = nc * 64;
        int em = rtmap[rt];
        int e = em >> 8, mt = em & 255;
        int cnt = counts[e];
        int row0 = base[e] + mt * 128;
        int rowEnd = base[e] + cnt;
        int arow = row0 + ar; if (arow > NSLOT - 1) arow = NSLOT - 1;

        f32x4 aG[2][4], aU[2][4];
        const f32x4 z = {0.f, 0.f, 0.f, 0.f};
#pragma unroll
        for (int i = 0; i < 2; i++)
#pragma unroll
            for (int j = 0; j < 4; j++) { aG[i][j] = z; aU[i][j] = z; }

        if constexpr (PK) {
            const unsigned short* wgpe = wgp + (size_t)e * DM * DI + (size_t)(nc0 + nb) * DM + bsrc;
            const unsigned short* wupe = wup + (size_t)e * DM * DI + (size_t)(nc0 + nb) * DM + bsrc;
            uint4 pa0, pa1, pa2, pa3, qg0, qg1, qu0, qu1;
            {
                const uint4* a_ = (const uint4*)(Xg + (size_t)arow * DM + ak);
                pa0 = a_[0]; pa1 = a_[1]; pa2 = a_[2]; pa3 = a_[3];
                qg0 = *(const uint4*)(wgpe);     qg1 = *(const uint4*)(wgpe + 8);
                qu0 = *(const uint4*)(wupe);     qu1 = *(const uint4*)(wupe + 8);
            }
            for (int kt = 0; kt < DM / 64; kt++) {
                *(uint4*)&As[ar * BKP + ak + 0]  = pa0;
                *(uint4*)&As[ar * BKP + ak + 8]  = pa1;
                *(uint4*)&As[ar * BKP + ak + 16] = pa2;
                *(uint4*)&As[ar * BKP + ak + 24] = pa3;
                *(uint4*)&Bg[boff0] = qg0;  *(uint4*)&Bg[boff1] = qg1;
                *(uint4*)&Bu[boff0] = qu0;  *(uint4*)&Bu[boff1] = qu1;
                __syncthreads();
                if (kt + 1 < DM / 64) {
                    int k0 = (kt + 1) * 64;
                    const uint4* a_ = (const uint4*)(Xg + (size_t)arow * DM + k0 + ak);
                    pa0 = a_[0]; pa1 = a_[1]; pa2 = a_[2]; pa3 = a_[3];
                    qg0 = *(const uint4*)(wgpe + k0);     qg1 = *(const uint4*)(wgpe + k0 + 8);
                    qu0 = *(const uint4*)(wupe + k0);     qu1 = *(const uint4*)(wupe + k0 + 8);
                }
#pragma unroll
                for (int s = 0; s < 2; s++) {
                    bf16x8 a0 = *(const bf16x8*)&As[(w * 32 + ln) * BKP + s * 32 + quad * 8];
                    bf16x8 a1 = *(const bf16x8*)&As[(w * 32 + 16 + ln) * BKP + s * 32 + quad * 8];
#pragma unroll
                    for (int j = 0; j < 4; j++) {
                        int nn = j * 16 + ln;
                        int grp = (s * 4 + quad) ^ ((nn >> 3) & 7);
                        bf16x8 bg = *(const bf16x8*)&Bg[nn * BKP + grp * 8];
                        bf16x8 bu = *(const bf16x8*)&Bu[nn * BKP + grp * 8];
                        aG[0][j] = mfma_bf16(a0, bg, aG[0][j]);
                        aG[1][j] = mfma_bf16(a1, bg, aG[1][j]);
                        aU[0][j] = mfma_bf16(a0, bu, aU[0][j]);
                        aU[1][j] = mfma_bf16(a1, bu, aU[1][j]);
                    }
                }
                __syncthreads();
            }
        } else {
            const float* wge = wg + (size_t)e * DM * DI;
            const float* wue = wu + (size_t)e * DM * DI;
            for (int kt = 0; kt < DM / 64; kt++) {
                int k0 = kt * 64;
                const uint4* asrc = (const uint4*)(Xg + (size_t)arow * DM + k0 + ak);
                uint4 av0 = asrc[0], av1 = asrc[1], av2 = asrc[2], av3 = asrc[3];
                const float* p0 = wge + (size_t)(k0 + 2 * kp) * DI + nc0 + n0;
                float4 g0 = *(const float4*)(p0),      g1 = *(const float4*)(p0 + 4);
                float4 g2 = *(const float4*)(p0 + DI), g3 = *(const float4*)(p0 + DI + 4);
                const float* p1 = wue + (size_t)(k0 + 2 * kp) * DI + nc0 + n0;
                float4 u0 = *(const float4*)(p1),      u1 = *(const float4*)(p1 + 4);
                float4 u2 = *(const float4*)(p1 + DI), u3 = *(const float4*)(p1 + DI + 4);
                *(uint4*)&As[ar * BKP + ak + 0]  = av0;
                *(uint4*)&As[ar * BKP + ak + 8]  = av1;
                *(uint4*)&As[ar * BKP + ak + 16] = av2;
                *(uint4*)&As[ar * BKP + ak + 24] = av3;
                unsigned short* bg = &Bg[n0 * BKP + kpsw2];
                unsigned short* bu = &Bu[n0 * BKP + kpsw2];
                *(unsigned*)(bg + 0 * BKP) = pack2bf(g0.x, g2.x);
                *(unsigned*)(bg + 1 * BKP) = pack2bf(g0.y, g2.y);
                *(unsigned*)(bg + 2 * BKP) = pack2bf(g0.z, g2.z);
                *(unsigned*)(bg + 3 * BKP) = pack2bf(g0.w, g2.w);
                *(unsigned*)(bg + 4 * BKP) = pack2bf(g1.x, g3.x);
                *(unsigned*)(bg + 5 * BKP) = pack2bf(g1.y, g3.y);
                *(unsigned*)(bg + 6 * BKP) = pack2bf(g1.z, g3.z);
                *(unsigned*)(bg + 7 * BKP) = pack2bf(g1.w, g3.w);
                *(unsigned*)(bu + 0 * BKP) = pack2bf(u0.x, u2.x);
                *(unsigned*)(bu + 1 * BKP) = pack2bf(u0.y, u2.y);
                *(unsigned*)(bu + 2 * BKP) = pack2bf(u0.z, u2.z);
                *(unsigned*)(bu + 3 * BKP) = pack2bf(u0.w, u2.w);
                *(unsigned*)(bu + 4 * BKP) = pack2bf(u1.x, u3.x);
                *(unsigned*)(bu + 5 * BKP) = pack2bf(u1.y, u3.y);
                *(unsigned*)(bu + 6 * BKP) = pack2bf(u1.z, u3.z);
                *(unsigned*)(bu + 7 * BKP) = pack2bf(u1.w, u3.w);
                __syncthreads();
#pragma unroll
                for (int s = 0; s < 2; s++) {
                    bf16x8 a0 = *(const bf16x8*)&As[(w * 32 + ln) * BKP + s * 32 + quad * 8];
                    bf16x8 a1 = *(const bf16x8*)&As[(w * 32 + 16 + ln) * BKP + s * 32 + quad * 8];
#pragma unroll
                    for (int j = 0; j < 4; j++) {
                        int nn = j * 16 + ln;
                        int grp = (s * 4 + quad) ^ ((nn >> 3) & 7);
                        bf16x8 bg8 = *(const bf16x8*)&Bg[nn * BKP + grp * 8];
                        bf16x8 bu8 = *(const bf16x8*)&Bu[nn * BKP + grp * 8];
                        aG[0][j] = mfma_bf16(a0, bg8, aG[0][j]);
                        aG[1][j] = mfma_bf16(a1, bg8, aG[1][j]);
                        aU[0][j] = mfma_bf16(a0, bu8, aU[0][j]);
                        aU[1][j] = mfma_bf16(a1, bu8, aU[1][j]);
                    }
                }
                __syncthreads();
            }
        }
        // epilogue: h = silu(g) * u, store bf16
#pragma unroll
        for (int i = 0; i < 2; i++)
#pragma unroll
            for (int r = 0; r < 4; r++) {
                int rl = w * 32 + i * 16 + quad * 4 + r;
                int grow = row0 + rl;
                if (grow < rowEnd) {
                    unsigned short* hp = H + (size_t)grow * DI + nc0 + ln;
#pragma unroll
                    for (int j = 0; j < 4; j++) {
                        float g = aG[i][j][r], u = aU[i][j][r];
                        float h = g * u / (1.f + __expf(-g));
                        hp[j * 16] = f2bf(h);
                    }
                }
            }
    }
}

// ---------------- phase 2: H @ Wd -> O (fp32, slot-major) -------------------
template<bool PK>
__global__ __launch_bounds__(256, 4) void k_ffn2(
    const unsigned short* __restrict__ H, const float* __restrict__ wd,
    const unsigned short* __restrict__ wdp,
    const int* __restrict__ counts, const int* __restrict__ base,
    const int* __restrict__ nrt_p, const unsigned short* __restrict__ rtmap,
    float* __restrict__ O)
{
    __shared__ unsigned short As[128 * BKP];
    __shared__ unsigned short Bd[64 * BKP];

    int tid = threadIdx.x;
    int w = tid >> 6, lane = tid & 63, quad = lane >> 4, ln = lane & 15;
    int ar = tid >> 1;
    int ak = (tid & 1) * 32;
    int kp = tid >> 3, n0 = (tid & 7) * 8;
    int kpsw2 = ((((kp >> 2) ^ (tid & 7)) << 2) | (kp & 3)) * 2;
    int nb = tid >> 2;
    int cA = (tid & 3) * 2;
    int boff0 = nb * BKP + ((cA ^ ((nb >> 3) & 7)) * 8);
    int boff1 = nb * BKP + (((cA + 1) ^ ((nb >> 3) & 7)) * 8);
    int bsrc = cA * 8;

    const int NCT = DM / 64;   // 16
    int nrt_v = nrt_p[0];
    int total = nrt_v * NCT;
    int wgid = (blockIdx.x & 7) * (gridDim.x >> 3) + (blockIdx.x >> 3);

    for (int tix = wgid; tix < total; tix += gridDim.x) {
        int nc = tix / nrt_v;              // nc-major
        int rt = tix - nc * nrt_v;
        int nc0 = nc * 64;
        int em = rtmap[rt];
        int e = em >> 8, mt = em & 255;
        int cnt = counts[e];
        int row0 = base[e] + mt * 128;
        int rowEnd = base[e] + cnt;
        int arow = row0 + ar; if (arow > NSLOT - 1) arow = NSLOT - 1;

        f32x4 acc[2][4];
        const f32x4 z = {0.f, 0.f, 0.f, 0.f};
#pragma unroll
        for (int i = 0; i < 2; i++)
#pragma unroll
            for (int j = 0; j < 4; j++) acc[i][j] = z;

        if constexpr (PK) {
            const unsigned short* wdpe = wdp + (size_t)e * DM * DI + (size_t)(nc0 + nb) * DI + bsrc;
            uint4 pa0, pa1, pa2, pa3, qd0, qd1;
            {
                const uint4* a_ = (const uint4*)(H + (size_t)arow * DI + ak);
                pa0 = a_[0]; pa1 = a_[1]; pa2 = a_[2]; pa3 = a_[3];
                qd0 = *(const uint4*)(wdpe);  qd1 = *(const uint4*)(wdpe + 8);
            }
            for (int kt = 0; kt < DI / 64; kt++) {
                *(uint4*)&As[ar * BKP + ak + 0]  = pa0;
                *(uint4*)&As[ar * BKP + ak + 8]  = pa1;
                *(uint4*)&As[ar * BKP + ak + 16] = pa2;
                *(uint4*)&As[ar * BKP + ak + 24] = pa3;
                *(uint4*)&Bd[boff0] = qd0;  *(uint4*)&Bd[boff1] = qd1;
                __syncthreads();
                if (kt + 1 < DI / 64) {
                    int k0 = (kt + 1) * 64;
                    const uint4* a_ = (const uint4*)(H + (size_t)arow * DI + k0 + ak);
                    pa0 = a_[0]; pa1 = a_[1]; pa2 = a_[2]; pa3 = a_[3];
                    qd0 = *(const uint4*)(wdpe + k0);  qd1 = *(const uint4*)(wdpe + k0 + 8);
                }
#pragma unroll
                for (int s = 0; s < 2; s++) {
                    bf16x8 a0 = *(const bf16x8*)&As[(w * 32 + ln) * BKP + s * 32 + quad * 8];
                    bf16x8 a1 = *(const bf16x8*)&As[(w * 32 + 16 + ln) * BKP + s * 32 + quad * 8];
#pragma unroll
                    for (int j = 0; j < 4; j++) {
                        int nn = j * 16 + ln;
                        int grp = (s * 4 + quad) ^ ((nn >> 3) & 7);
                        bf16x8 bd = *(const bf16x8*)&Bd[nn * BKP + grp * 8];
                        acc[0][j] = mfma_bf16(a0, bd, acc[0][j]);
                        acc[1][j] = mfma_bf16(a1, bd, acc[1][j]);
                    }
                }
                __syncthreads();
            }
        } else {
            const float* wde = wd + (size_t)e * DI * DM;
            for (int kt = 0; kt < DI / 64; kt++) {
                int k0 = kt * 64;
                const uint4* asrc = (const uint4*)(H + (size_t)arow * DI + k0 + ak);
                uint4 av0 = asrc[0], av1 = asrc[1], av2 = asrc[2], av3 = asrc[3];
                const float* p0 = wde + (size_t)(k0 + 2 * kp) * DM + nc0 + n0;
                float4 d0 = *(const float4*)(p0),      d1 = *(const float4*)(p0 + 4);
                float4 d2 = *(const float4*)(p0 + DM), d3 = *(const float4*)(p0 + DM + 4);
                *(uint4*)&As[ar * BKP + ak + 0]  = av0;
                *(uint4*)&As[ar * BKP + ak + 8]  = av1;
                *(uint4*)&As[ar * BKP + ak + 16] = av2;
                *(uint4*)&As[ar * BKP + ak + 24] = av3;
                unsigned short* bd = &Bd[n0 * BKP + kpsw2];
                *(unsigned*)(bd + 0 * BKP) = pack2bf(d0.x, d2.x);
                *(unsigned*)(bd + 1 * BKP) = pack2bf(d0.y, d2.y);
                *(unsigned*)(bd + 2 * BKP) = pack2bf(d0.z, d2.z);
                *(unsigned*)(bd + 3 * BKP) = pack2bf(d0.w, d2.w);
                *(unsigned*)(bd + 4 * BKP) = pack2bf(d1.x, d3.x);
                *(unsigned*)(bd + 5 * BKP) = pack2bf(d1.y, d3.y);
                *(unsigned*)(bd + 6 * BKP) = pack2bf(d1.z, d3.z);
                *(unsigned*)(bd + 7 * BKP) = pack2bf(d1.w, d3.w);
                __syncthreads();
#pragma unroll
                for (int s = 0; s < 2; s++) {
                    bf16x8 a0 = *(const bf16x8*)&As[(w * 32 + ln) * BKP + s * 32 + quad * 8];
                    bf16x8 a1 = *(const bf16x8*)&As[(w * 32 + 16 + ln) * BKP + s * 32 + quad * 8];
#pragma unroll
                    for (int j = 0; j < 4; j++) {
                        int nn = j * 16 + ln;
                        int grp = (s * 4 + quad) ^ ((nn >> 3) & 7);
                        bf16x8 bd8 = *(const bf16x8*)&Bd[nn * BKP + grp * 8];
                        acc[0][j] = mfma_bf16(a0, bd8, acc[0][j]);
                        acc[1][j] = mfma_bf16(a1, bd8, acc[1][j]);
                    }
                }
                __syncthreads();
            }
        }
#pragma unroll
        for (int i = 0; i < 2; i++)
#pragma unroll
            for (int r = 0; r < 4; r++) {
                int rl = w * 32 + i * 16 + quad * 4 + r;
                int grow = row0 + rl;
                if (grow < rowEnd) {
                    float* op = O + (size_t)grow * DM + nc0 + ln;
#pragma unroll
                    for (int j = 0; j < 4; j++) op[j * 16] = acc[i][j][r];
                }
            }
    }
}

// ---------------- combine: out[n] = w0*O[s0] + w1*O[s1] ---------------------
__global__ __launch_bounds__(256) void k_combine(
    const float* __restrict__ O, const int* __restrict__ slots,
    const float* __restrict__ tw, float* __restrict__ out)
{
    int n = blockIdx.x;
    int s0 = slots[2 * n], s1 = slots[2 * n + 1];
    float w0 = tw[2 * n], w1 = tw[2 * n + 1];
    const float4* o0 = (const float4*)(O + (size_t)s0 * DM);
    const float4* o1 = (const float4*)(O + (size_t)s1 * DM);
    float4 a = o0[threadIdx.x], b = o1[threadIdx.x];
    float4 r;
    r.x = w0 * a.x + w1 * b.x;
    r.y = w0 * a.y + w1 * b.y;
    r.z = w0 * a.z + w1 * b.z;
    r.w = w0 * a.w + w1 * b.w;
    ((float4*)(out + (size_t)n * DM))[threadIdx.x] = r;
}

extern "C" void kernel_launch(void* const* d_in, const int* in_sizes, int n_in,
                              void* d_out, int out_size, void* d_ws, size_t ws_size,
                              hipStream_t stream)
{
    const float* x  = (const float*)d_in[0];
    const float* wr = (const float*)d_in[1];
    const float* wg = (const float*)d_in[2];
    const float* wu = (const float*)d_in[3];
    const float* wd = (const float*)d_in[4];
    float* out = (float*)d_out;

    char* ws = (char*)d_ws;
    int*   counts  = (int*)(ws + 0);
    float* probsum = (float*)(ws + 64);
    int*   base    = (int*)(ws + 96);
    int*   nrt     = (int*)(ws + 128);
    unsigned short* rtmap = (unsigned short*)(ws + 132);   // 40 x u16 <= 212
    int*   te      = (int*)(ws + 256);
    float* tw      = (float*)(ws + 256 + 16384);
    int*   slots   = (int*)(ws + 256 + 32768);

    size_t off_Xg = 49408;
    size_t off_Hb = off_Xg + (size_t)NSLOT * DM * 2;
    size_t off_O  = off_Hb + (size_t)NSLOT * DI * 2;
    size_t off_Wg = off_O + (size_t)NSLOT * DM * 4;
    size_t off_Wu = off_Wg + (size_t)NE * DM * DI * 2;
    size_t off_Wd = off_Wu + (size_t)NE * DM * DI * 2;
    size_t end_GU = off_Wd;
    size_t end_D  = off_Wd + (size_t)NE * DM * DI * 2;

    unsigned short* Xg  = (unsigned short*)(ws + off_Xg);
    unsigned short* Hb  = (unsigned short*)(ws + off_Hb);
    float*          O   = (float*)(ws + off_O);
    unsigned short* Wgp = (unsigned short*)(ws + off_Wg);
    unsigned short* Wup = (unsigned short*)(ws + off_Wu);
    unsigned short* Wdp = (unsigned short*)(ws + off_Wd);

    // Control arrays overlaid at the head of the O buffer (O is written by
    // k_ffn2 only after gather has consumed these; zero workspace growth).
    unsigned*       hist     = (unsigned*)(ws + off_O);               // 2 KB
    unsigned short* blockoff = (unsigned short*)(ws + off_O + 4096);  // 8 KB

    bool pkGU = ws_size >= end_GU;
    bool pkD  = ws_size >= end_D;

    hipMemsetAsync(ws, 0, 128, stream);   // zeroes probsum (and counts header)
    k_router<<<NBLK, 256, 0, stream>>>(x, wr, probsum, te, tw, hist);
    k_finalize<<<1, 512, 0, stream>>>(hist, probsum, counts, base, nrt, rtmap,
                                      blockoff, out + (size_t)N_TOK * DM);
    k_gather<<<NBLK, 256, 0, stream>>>(x, te, blockoff, slots, Xg);

    if (pkGU)
        k_pack2<<<dim3(DI / 64, DM / 64, 2 * NE), 256, 0, stream>>>(
            wg, Wgp, wu, Wup, DM, DI);
    if (pkD)
        k_pack<<<dim3(DM / 64, DI / 64, NE), 256, 0, stream>>>(wd, Wdp, DI, DM);

    // grid = max possible active tiles (divisible by 8 for the XCD swizzle)
    if (pkGU)
        k_ffn1<true><<<MAXRT * (DI / 64), 256, 0, stream>>>(
            Xg, wg, wu, Wgp, Wup, counts, base, nrt, rtmap, Hb);
    else
        k_ffn1<false><<<MAXRT * (DI / 64), 256, 0, stream>>>(
            Xg, wg, wu, Wgp, Wup, counts, base, nrt, rtmap, Hb);

    if (pkD)
        k_ffn2<true><<<MAXRT * (DM / 64), 256, 0, stream>>>(
            Hb, wd, Wdp, counts, base, nrt, rtmap, O);
    else
        k_ffn2<false><<<MAXRT * (DM / 64), 256, 0, stream>>>(
            Hb, wd, Wdp, counts, base, nrt, rtmap, O);

    k_combine<<<N_TOK, 256, 0, stream>>>(O, slots, tw, out);
}

// Round 6
// 458.782 us; speedup vs baseline: 1.0334x; 1.0334x over previous
//
#include <hip/hip_runtime.h>
#include <stdint.h>

#define N_TOK 2048
#define DM 1024
#define DI 2816
#define NE 8
#define NSLOT (N_TOK * 2)   // 4096 (token, expert) slots
#define BKP 72              // LDS k-stride (shorts): 64 + 8 pad
#define MAXRT 40            // max row tiles: sum_e ceil(cnt_e/128) <= 39
#define NBLK (N_TOK / 4)    // 512 router/gather blocks (4 tokens each)

typedef __bf16 bf16x8 __attribute__((ext_vector_type(8)));
typedef float f32x4 __attribute__((ext_vector_type(4)));

__device__ __forceinline__ unsigned short f2bf(float f) {
    unsigned u = __builtin_bit_cast(unsigned, f);
    u += 0x7fffu + ((u >> 16) & 1u);   // RNE
    return (unsigned short)(u >> 16);
}
__device__ __forceinline__ unsigned pack2bf(float a, float b) {
    return (unsigned)f2bf(a) | ((unsigned)f2bf(b) << 16);
}

__device__ __forceinline__ f32x4 mfma_bf16(bf16x8 a, bf16x8 b, f32x4 c) {
    return __builtin_amdgcn_mfma_f32_16x16x32_bf16(a, b, c, 0, 0, 0);
}

// ---------------- router: logits, softmax, top2, per-block hist -------------
__global__ __launch_bounds__(256) void k_router(
    const float* __restrict__ x, const float* __restrict__ wr,
    float* __restrict__ probsum, int* __restrict__ te, float* __restrict__ tw,
    unsigned* __restrict__ hist)
{
    __shared__ int te_s[8];
    __shared__ float ps[4][NE];
    int w = threadIdx.x >> 6, lane = threadIdx.x & 63;
    int n = blockIdx.x * 4 + w;
    const float* xr = x + (size_t)n * DM;

    float acc[NE];
#pragma unroll
    for (int e = 0; e < NE; e++) acc[e] = 0.f;
#pragma unroll
    for (int it = 0; it < DM / 64; it++) {
        float xv = xr[lane + it * 64];
#pragma unroll
        for (int e = 0; e < NE; e++) acc[e] += xv * wr[e * DM + lane + it * 64];
    }
#pragma unroll
    for (int e = 0; e < NE; e++) {
        float v = acc[e];
#pragma unroll
        for (int off = 32; off; off >>= 1) v += __shfl_xor(v, off);
        acc[e] = v;
    }
    float m = acc[0];
#pragma unroll
    for (int e = 1; e < NE; e++) m = fmaxf(m, acc[e]);
    float p[NE], s = 0.f;
#pragma unroll
    for (int e = 0; e < NE; e++) { p[e] = __expf(acc[e] - m); s += p[e]; }
    float inv = 1.f / s;
#pragma unroll
    for (int e = 0; e < NE; e++) p[e] *= inv;
    int i0 = 0;
#pragma unroll
    for (int e = 1; e < NE; e++) if (p[e] > p[i0]) i0 = e;
    int i1 = (i0 == 0) ? 1 : 0;
#pragma unroll
    for (int e = 0; e < NE; e++) if (e != i0 && p[e] > p[i1]) i1 = e;
    float w0 = p[i0] / (p[i0] + p[i1]);
    float w1 = 1.f - w0;

    if (lane == 0) {
        te[2 * n] = i0; te[2 * n + 1] = i1;
        tw[2 * n] = w0; tw[2 * n + 1] = w1;
        te_s[2 * w] = i0; te_s[2 * w + 1] = i1;
    }
    if (lane < NE) ps[w][lane] = p[lane];   // p identical across lanes
    __syncthreads();

    if (threadIdx.x < NE) {
        float s4 = ps[0][threadIdx.x] + ps[1][threadIdx.x] +
                   ps[2][threadIdx.x] + ps[3][threadIdx.x];
        atomicAdd(&probsum[threadIdx.x], s4);   // 8 per block, non-returning
    }
    if (w == 0) {
        unsigned v = 0;
        if (lane < NE) {
            int c = 0;
#pragma unroll
            for (int i = 0; i < 8; i++) c += (te_s[i] == lane);
            v = (unsigned)c << (4 * lane);
        }
        v |= __shfl_xor(v, 1); v |= __shfl_xor(v, 2); v |= __shfl_xor(v, 4);
        if (lane == 0) hist[blockIdx.x] = v;
    }
}

// ---------------- finalize: counts/base/rtmap/aux + per-block slot offsets --
__global__ __launch_bounds__(512) void k_finalize(
    const unsigned* __restrict__ hist, const float* __restrict__ probsum,
    int* __restrict__ counts, int* __restrict__ base,
    int* __restrict__ nrt_out, unsigned short* __restrict__ rtmap,
    unsigned short* __restrict__ blockoff, float* __restrict__ aux_out)
{
    __shared__ int cnts_s[NE], base_s[NE];
    int tid = threadIdx.x;
    int e = tid >> 6, lane = tid & 63;

    int c[8], t = 0;
#pragma unroll
    for (int j = 0; j < 8; j++) {
        c[j] = (int)((hist[lane * 8 + j] >> (4 * e)) & 15u);
        t += c[j];
    }
    int incl = t;
#pragma unroll
    for (int off = 1; off < 64; off <<= 1) {
        int v = __shfl_up(incl, off);
        if (lane >= off) incl += v;
    }
    int excl = incl - t;
    if (lane == 63) cnts_s[e] = incl;
    __syncthreads();

    if (tid == 0) {
        int b = 0, nrt = 0; float aux = 0.f;
        for (int ee = 0; ee < NE; ee++) {
            int cc = cnts_s[ee];
            base_s[ee] = b;
            base[ee] = b;
            counts[ee] = cc;
            b += cc;
            aux += ((float)cc / (float)(N_TOK * 2)) *
                   (probsum[ee] / (float)N_TOK);
            int nt = (cc + 127) >> 7;
            for (int mt = 0; mt < nt; mt++)
                rtmap[nrt++] = (unsigned short)((ee << 8) | mt);
        }
        nrt_out[0] = nrt;
        aux_out[0] = aux * (float)NE;
    }
    __syncthreads();

    int run = base_s[e] + excl;
#pragma unroll
    for (int j = 0; j < 8; j++) {
        blockoff[(lane * 8 + j) * NE + e] = (unsigned short)run;
        run += c[j];
    }
}

// ---------------- gather: deterministic slots + fp32->bf16 copy -------------
__global__ __launch_bounds__(256) void k_gather(
    const float* __restrict__ x, const int* __restrict__ te,
    const unsigned short* __restrict__ blockoff,
    int* __restrict__ slots, unsigned short* __restrict__ Xg)
{
    __shared__ int te_s[8];
    int w = threadIdx.x >> 6, lane = threadIdx.x & 63;
    int n = blockIdx.x * 4 + w;
    if (lane == 0) {
        te_s[2 * w] = te[2 * n];
        te_s[2 * w + 1] = te[2 * n + 1];
    }
    __syncthreads();
    int s0 = 0, s1 = 0;
    if (lane == 0) {
        int i0 = 2 * w, i1 = 2 * w + 1;
        int e0 = te_s[i0], e1 = te_s[i1];
        int r0 = 0, r1 = 0;
        for (int j = 0; j < i0; j++) r0 += (te_s[j] == e0);
        for (int j = 0; j < i1; j++) r1 += (te_s[j] == e1);
        s0 = blockoff[blockIdx.x * NE + e0] + r0;
        s1 = blockoff[blockIdx.x * NE + e1] + r1;
        slots[2 * n] = s0; slots[2 * n + 1] = s1;
    }
    s0 = __shfl(s0, 0); s1 = __shfl(s1, 0);

    const float4* xr = (const float4*)(x + (size_t)n * DM);
    float4 f0 = xr[lane * 4 + 0], f1 = xr[lane * 4 + 1];
    float4 f2 = xr[lane * 4 + 2], f3 = xr[lane * 4 + 3];
    uint4 lo = make_uint4(pack2bf(f0.x, f0.y), pack2bf(f0.z, f0.w),
                          pack2bf(f1.x, f1.y), pack2bf(f1.z, f1.w));
    uint4 hi = make_uint4(pack2bf(f2.x, f2.y), pack2bf(f2.z, f2.w),
                          pack2bf(f3.x, f3.y), pack2bf(f3.z, f3.w));
    uint4* d0 = (uint4*)(Xg + (size_t)s0 * DM) + lane * 2;
    uint4* d1 = (uint4*)(Xg + (size_t)s1 * DM) + lane * 2;
    d0[0] = lo; d0[1] = hi;
    d1[0] = lo; d1[1] = hi;
}

// ---------------- phase 1: [Xg rows] @ (Wg|Wu) fp32 -> silu*u -> H (bf16) ---
// rt-major compacted tile order (round-4 proven); weights read fp32 directly,
// converted to bf16 during LDS staging (no separate pack pass).
__global__ __launch_bounds__(256, 4) void k_ffn1(
    const unsigned short* __restrict__ Xg,
    const float* __restrict__ wg, const float* __restrict__ wu,
    const int* __restrict__ counts, const int* __restrict__ base,
    const int* __restrict__ nrt_p, const unsigned short* __restrict__ rtmap,
    unsigned short* __restrict__ H)
{
    __shared__ unsigned short As[128 * BKP];
    __shared__ unsigned short Bg[64 * BKP];
    __shared__ unsigned short Bu[64 * BKP];

    int tid = threadIdx.x;
    int w = tid >> 6, lane = tid & 63, quad = lane >> 4, ln = lane & 15;
    int ar = tid >> 1;
    int ak = (tid & 1) * 32;
    // fp32-staging map
    int kp = tid >> 3, n0 = (tid & 7) * 8;
    int kpsw2 = ((((kp >> 2) ^ (tid & 7)) << 2) | (kp & 3)) * 2;

    const int NCT = DI / 64;   // 44
    int total = nrt_p[0] * NCT;

    for (int tix = blockIdx.x; tix < total; tix += gridDim.x) {
        int rt = tix / NCT;                // rt-major (round-4 proven)
        int nc0 = (tix - rt * NCT) * 64;
        int em = rtmap[rt];
        int e = em >> 8, mt = em & 255;
        int cnt = counts[e];
        int row0 = base[e] + mt * 128;
        int rowEnd = base[e] + cnt;
        int arow = row0 + ar; if (arow > NSLOT - 1) arow = NSLOT - 1;

        f32x4 aG[2][4], aU[2][4];
        const f32x4 z = {0.f, 0.f, 0.f, 0.f};
#pragma unroll
        for (int i = 0; i < 2; i++)
#pragma unroll
            for (int j = 0; j < 4; j++) { aG[i][j] = z; aU[i][j] = z; }

        const float* wge = wg + (size_t)e * DM * DI;
        const float* wue = wu + (size_t)e * DM * DI;
        for (int kt = 0; kt < DM / 64; kt++) {
            int k0 = kt * 64;
            const uint4* asrc = (const uint4*)(Xg + (size_t)arow * DM + k0 + ak);
            uint4 av0 = asrc[0], av1 = asrc[1], av2 = asrc[2], av3 = asrc[3];
            const float* p0 = wge + (size_t)(k0 + 2 * kp) * DI + nc0 + n0;
            float4 g0 = *(const float4*)(p0),      g1 = *(const float4*)(p0 + 4);
            float4 g2 = *(const float4*)(p0 + DI), g3 = *(const float4*)(p0 + DI + 4);
            const float* p1 = wue + (size_t)(k0 + 2 * kp) * DI + nc0 + n0;
            float4 u0 = *(const float4*)(p1),      u1 = *(const float4*)(p1 + 4);
            float4 u2 = *(const float4*)(p1 + DI), u3 = *(const float4*)(p1 + DI + 4);
            *(uint4*)&As[ar * BKP + ak + 0]  = av0;
            *(uint4*)&As[ar * BKP + ak + 8]  = av1;
            *(uint4*)&As[ar * BKP + ak + 16] = av2;
            *(uint4*)&As[ar * BKP + ak + 24] = av3;
            unsigned short* bg = &Bg[n0 * BKP + kpsw2];
            unsigned short* bu = &Bu[n0 * BKP + kpsw2];
            *(unsigned*)(bg + 0 * BKP) = pack2bf(g0.x, g2.x);
            *(unsigned*)(bg + 1 * BKP) = pack2bf(g0.y, g2.y);
            *(unsigned*)(bg + 2 * BKP) = pack2bf(g0.z, g2.z);
            *(unsigned*)(bg + 3 * BKP) = pack2bf(g0.w, g2.w);
            *(unsigned*)(bg + 4 * BKP) = pack2bf(g1.x, g3.x);
            *(unsigned*)(bg + 5 * BKP) = pack2bf(g1.y, g3.y);
            *(unsigned*)(bg + 6 * BKP) = pack2bf(g1.z, g3.z);
            *(unsigned*)(bg + 7 * BKP) = pack2bf(g1.w, g3.w);
            *(unsigned*)(bu + 0 * BKP) = pack2bf(u0.x, u2.x);
            *(unsigned*)(bu + 1 * BKP) = pack2bf(u0.y, u2.y);
            *(unsigned*)(bu + 2 * BKP) = pack2bf(u0.z, u2.z);
            *(unsigned*)(bu + 3 * BKP) = pack2bf(u0.w, u2.w);
            *(unsigned*)(bu + 4 * BKP) = pack2bf(u1.x, u3.x);
            *(unsigned*)(bu + 5 * BKP) = pack2bf(u1.y, u3.y);
            *(unsigned*)(bu + 6 * BKP) = pack2bf(u1.z, u3.z);
            *(unsigned*)(bu + 7 * BKP) = pack2bf(u1.w, u3.w);
            __syncthreads();
#pragma unroll
            for (int s = 0; s < 2; s++) {
                bf16x8 a0 = *(const bf16x8*)&As[(w * 32 + ln) * BKP + s * 32 + quad * 8];
                bf16x8 a1 = *(const bf16x8*)&As[(w * 32 + 16 + ln) * BKP + s * 32 + quad * 8];
#pragma unroll
                for (int j = 0; j < 4; j++) {
                    int nn = j * 16 + ln;
                    int grp = (s * 4 + quad) ^ ((nn >> 3) & 7);
                    bf16x8 bg8 = *(const bf16x8*)&Bg[nn * BKP + grp * 8];
                    bf16x8 bu8 = *(const bf16x8*)&Bu[nn * BKP + grp * 8];
                    aG[0][j] = mfma_bf16(a0, bg8, aG[0][j]);
                    aG[1][j] = mfma_bf16(a1, bg8, aG[1][j]);
                    aU[0][j] = mfma_bf16(a0, bu8, aU[0][j]);
                    aU[1][j] = mfma_bf16(a1, bu8, aU[1][j]);
                }
            }
            __syncthreads();
        }
        // epilogue: h = silu(g) * u, store bf16
#pragma unroll
        for (int i = 0; i < 2; i++)
#pragma unroll
            for (int r = 0; r < 4; r++) {
                int rl = w * 32 + i * 16 + quad * 4 + r;
                int grow = row0 + rl;
                if (grow < rowEnd) {
                    unsigned short* hp = H + (size_t)grow * DI + nc0 + ln;
#pragma unroll
                    for (int j = 0; j < 4; j++) {
                        float g = aG[i][j][r], u = aU[i][j][r];
                        float h = g * u / (1.f + __expf(-g));
                        hp[j * 16] = f2bf(h);
                    }
                }
            }
    }
}

// ---------------- phase 2: H @ Wd (fp32) -> O (fp32, slot-major) ------------
__global__ __launch_bounds__(256, 4) void k_ffn2(
    const unsigned short* __restrict__ H, const float* __restrict__ wd,
    const int* __restrict__ counts, const int* __restrict__ base,
    const int* __restrict__ nrt_p, const unsigned short* __restrict__ rtmap,
    float* __restrict__ O)
{
    __shared__ unsigned short As[128 * BKP];
    __shared__ unsigned short Bd[64 * BKP];

    int tid = threadIdx.x;
    int w = tid >> 6, lane = tid & 63, quad = lane >> 4, ln = lane & 15;
    int ar = tid >> 1;
    int ak = (tid & 1) * 32;
    int kp = tid >> 3, n0 = (tid & 7) * 8;
    int kpsw2 = ((((kp >> 2) ^ (tid & 7)) << 2) | (kp & 3)) * 2;

    const int NCT = DM / 64;   // 16
    int total = nrt_p[0] * NCT;

    for (int tix = blockIdx.x; tix < total; tix += gridDim.x) {
        int rt = tix >> 4;                 // NCT = 16, rt-major
        int nc0 = (tix & 15) * 64;
        int em = rtmap[rt];
        int e = em >> 8, mt = em & 255;
        int cnt = counts[e];
        int row0 = base[e] + mt * 128;
        int rowEnd = base[e] + cnt;
        int arow = row0 + ar; if (arow > NSLOT - 1) arow = NSLOT - 1;

        f32x4 acc[2][4];
        const f32x4 z = {0.f, 0.f, 0.f, 0.f};
#pragma unroll
        for (int i = 0; i < 2; i++)
#pragma unroll
            for (int j = 0; j < 4; j++) acc[i][j] = z;

        const float* wde = wd + (size_t)e * DI * DM;
        for (int kt = 0; kt < DI / 64; kt++) {
            int k0 = kt * 64;
            const uint4* asrc = (const uint4*)(H + (size_t)arow * DI + k0 + ak);
            uint4 av0 = asrc[0], av1 = asrc[1], av2 = asrc[2], av3 = asrc[3];
            const float* p0 = wde + (size_t)(k0 + 2 * kp) * DM + nc0 + n0;
            float4 d0 = *(const float4*)(p0),      d1 = *(const float4*)(p0 + 4);
            float4 d2 = *(const float4*)(p0 + DM), d3 = *(const float4*)(p0 + DM + 4);
            *(uint4*)&As[ar * BKP + ak + 0]  = av0;
            *(uint4*)&As[ar * BKP + ak + 8]  = av1;
            *(uint4*)&As[ar * BKP + ak + 16] = av2;
            *(uint4*)&As[ar * BKP + ak + 24] = av3;
            unsigned short* bd = &Bd[n0 * BKP + kpsw2];
            *(unsigned*)(bd + 0 * BKP) = pack2bf(d0.x, d2.x);
            *(unsigned*)(bd + 1 * BKP) = pack2bf(d0.y, d2.y);
            *(unsigned*)(bd + 2 * BKP) = pack2bf(d0.z, d2.z);
            *(unsigned*)(bd + 3 * BKP) = pack2bf(d0.w, d2.w);
            *(unsigned*)(bd + 4 * BKP) = pack2bf(d1.x, d3.x);
            *(unsigned*)(bd + 5 * BKP) = pack2bf(d1.y, d3.y);
            *(unsigned*)(bd + 6 * BKP) = pack2bf(d1.z, d3.z);
            *(unsigned*)(bd + 7 * BKP) = pack2bf(d1.w, d3.w);
            __syncthreads();
#pragma unroll
            for (int s = 0; s < 2; s++) {
                bf16x8 a0 = *(const bf16x8*)&As[(w * 32 + ln) * BKP + s * 32 + quad * 8];
                bf16x8 a1 = *(const bf16x8*)&As[(w * 32 + 16 + ln) * BKP + s * 32 + quad * 8];
#pragma unroll
                for (int j = 0; j < 4; j++) {
                    int nn = j * 16 + ln;
                    int grp = (s * 4 + quad) ^ ((nn >> 3) & 7);
                    bf16x8 bd8 = *(const bf16x8*)&Bd[nn * BKP + grp * 8];
                    acc[0][j] = mfma_bf16(a0, bd8, acc[0][j]);
                    acc[1][j] = mfma_bf16(a1, bd8, acc[1][j]);
                }
            }
            __syncthreads();
        }
#pragma unroll
        for (int i = 0; i < 2; i++)
#pragma unroll
            for (int r = 0; r < 4; r++) {
                int rl = w * 32 + i * 16 + quad * 4 + r;
                int grow = row0 + rl;
                if (grow < rowEnd) {
                    float* op = O + (size_t)grow * DM + nc0 + ln;
#pragma unroll
                    for (int j = 0; j < 4; j++) op[j * 16] = acc[i][j][r];
                }
            }
    }
}

// ---------------- combine: out[n] = w0*O[s0] + w1*O[s1] ---------------------
__global__ __launch_bounds__(256) void k_combine(
    const float* __restrict__ O, const int* __restrict__ slots,
    const float* __restrict__ tw, float* __restrict__ out)
{
    int n = blockIdx.x;
    int s0 = slots[2 * n], s1 = slots[2 * n + 1];
    float w0 = tw[2 * n], w1 = tw[2 * n + 1];
    const float4* o0 = (const float4*)(O + (size_t)s0 * DM);
    const float4* o1 = (const float4*)(O + (size_t)s1 * DM);
    float4 a = o0[threadIdx.x], b = o1[threadIdx.x];
    float4 r;
    r.x = w0 * a.x + w1 * b.x;
    r.y = w0 * a.y + w1 * b.y;
    r.z = w0 * a.z + w1 * b.z;
    r.w = w0 * a.w + w1 * b.w;
    ((float4*)(out + (size_t)n * DM))[threadIdx.x] = r;
}

extern "C" void kernel_launch(void* const* d_in, const int* in_sizes, int n_in,
                              void* d_out, int out_size, void* d_ws, size_t ws_size,
                              hipStream_t stream)
{
    const float* x  = (const float*)d_in[0];
    const float* wr = (const float*)d_in[1];
    const float* wg = (const float*)d_in[2];
    const float* wu = (const float*)d_in[3];
    const float* wd = (const float*)d_in[4];
    float* out = (float*)d_out;

    char* ws = (char*)d_ws;
    int*   counts  = (int*)(ws + 0);
    float* probsum = (float*)(ws + 64);
    int*   base    = (int*)(ws + 96);
    int*   nrt     = (int*)(ws + 128);
    unsigned short* rtmap = (unsigned short*)(ws + 132);   // 40 x u16 <= 212
    int*   te      = (int*)(ws + 256);
    float* tw      = (float*)(ws + 256 + 16384);
    int*   slots   = (int*)(ws + 256 + 32768);

    size_t off_Xg = 49408;
    size_t off_Hb = off_Xg + (size_t)NSLOT * DM * 2;
    size_t off_O  = off_Hb + (size_t)NSLOT * DI * 2;

    unsigned short* Xg  = (unsigned short*)(ws + off_Xg);
    unsigned short* Hb  = (unsigned short*)(ws + off_Hb);
    float*          O   = (float*)(ws + off_O);

    // Control arrays overlaid at the head of the O buffer (O is written by
    // k_ffn2 only after gather has consumed these; zero workspace growth).
    unsigned*       hist     = (unsigned*)(ws + off_O);               // 2 KB
    unsigned short* blockoff = (unsigned short*)(ws + off_O + 4096);  // 8 KB

    hipMemsetAsync(ws, 0, 128, stream);   // zeroes probsum (and counts header)
    k_router<<<NBLK, 256, 0, stream>>>(x, wr, probsum, te, tw, hist);
    k_finalize<<<1, 512, 0, stream>>>(hist, probsum, counts, base, nrt, rtmap,
                                      blockoff, out + (size_t)N_TOK * DM);
    k_gather<<<NBLK, 256, 0, stream>>>(x, te, blockoff, slots, Xg);

    // grid = max possible active tiles
    k_ffn1<<<MAXRT * (DI / 64), 256, 0, stream>>>(
        Xg, wg, wu, counts, base, nrt, rtmap, Hb);
    k_ffn2<<<MAXRT * (DM / 64), 256, 0, stream>>>(
        Hb, wd, counts, base, nrt, rtmap, O);

    k_combine<<<N_TOK, 256, 0, stream>>>(O, slots, tw, out);
}